// Round 3
// baseline (356.172 us; speedup 1.0000x reference)
//
#include <hip/hip_runtime.h>
#include <hip/hip_bf16.h>

// NeuroselectiveLinear: y = gather(x, in_idx) @ W^T + b scattered into a
// zeroed [B,S,4096] buffer.
// Pipeline: memset(pos) -> prep (bf16 W + inverse pos map) -> gather
// (coalesced x -> compact bf16 Xa) -> gemmx (fused MFMA GEMM over full K in
// LDS + dense 4096-wide row write with zero merge; ys aliases As in LDS).

typedef unsigned short u16;
typedef u16   u16x4 __attribute__((ext_vector_type(4)));
typedef int   i32x4 __attribute__((ext_vector_type(4)));
typedef float f32x4 __attribute__((ext_vector_type(4)));
typedef __bf16 bf16x8 __attribute__((ext_vector_type(8)));

constexpr int IN_F  = 4096;
constexpr int OUT_F = 4096;
constexpr int AI    = 1024;      // ACTIVE_IN  (K)
constexpr int AO    = 1024;      // ACTIVE_OUT (N)
constexpr int M_ROWS = 4 * 2048; // 8192
constexpr int BM    = 16;        // rows per gemmx block; grid 512 -> 2 blocks/CU

__device__ __forceinline__ u16 f2bf(float f) {
    union { __hip_bfloat16 h; u16 u; } cv;
    cv.h = __float2bfloat16(f);   // RNE
    return cv.u;
}
__device__ __forceinline__ float bf2f(u16 u) {
    union { float f; unsigned int i; } cv;
    cv.i = ((unsigned int)u) << 16;
    return cv.f;
}

// pos[out_idx[j]] = j  (pos pre-memset to -1 via hipMemsetAsync 0xFF)
// Wb = bf16(W), row-major [AO][AI]
__global__ void prep_kernel(const float* __restrict__ W,
                            const int* __restrict__ out_idx,
                            u16* __restrict__ Wb, int* __restrict__ pos) {
    int t = blockIdx.x * blockDim.x + threadIdx.x; // 0..262143
    if (t < AO) pos[out_idx[t]] = t;
    f32x4 w = reinterpret_cast<const f32x4*>(W)[t];
    u16x4 v;
    v.x = f2bf(w.x); v.y = f2bf(w.y); v.z = f2bf(w.z); v.w = f2bf(w.w);
    reinterpret_cast<u16x4*>(Wb)[t] = v;
}

// One block per row: coalesced dense row load -> LDS, then LDS gather.
__global__ __launch_bounds__(256)
void gather_kernel(const float* __restrict__ x,
                   const int* __restrict__ in_idx,
                   u16* __restrict__ Xa) {
    __shared__ float xrow[IN_F];
    const int m = blockIdx.x;
    const int t = threadIdx.x;
    const f32x4* src = reinterpret_cast<const f32x4*>(x + (size_t)m * IN_F);
#pragma unroll
    for (int i = 0; i < 4; ++i)
        *reinterpret_cast<f32x4*>(&xrow[i * 1024 + t * 4]) = src[i * 256 + t];
    __syncthreads();
    i32x4 idx = reinterpret_cast<const i32x4*>(in_idx)[t];
    u16x4 v;
    v.x = f2bf(xrow[idx.x]);
    v.y = f2bf(xrow[idx.y]);
    v.z = f2bf(xrow[idx.z]);
    v.w = f2bf(xrow[idx.w]);
    reinterpret_cast<u16x4*>(Xa + (size_t)m * AI)[t] = v;
}

// Fused GEMM + dense write. Block = 16 rows x all 1024 active outputs.
// Full K resident in swizzled LDS (no staging loop / no per-K barriers).
// B-fragments stream from L2-resident Wb. Epilogue parks y as bf16 in LDS
// (aliasing the dead A-tile), then writes dense 4096-wide rows with zero
// merge via pos[]. 512 thr (8 waves), LDS ~65.5 KB -> 2 blocks/CU.
union TileU {
    u16 As[BM][1024];        // 32 KB, XOR-swizzled: byte col ^= (row&15)<<4
    u16 ys[BM][1040];        // 33.3 KB (pad keeps write banks spread)
    char bytes[BM * 1040 * 2];
};

__global__ __launch_bounds__(512, 4)
void gemmx_kernel(const u16* __restrict__ Xa, const u16* __restrict__ Wb,
                  const float* __restrict__ bias, const int* __restrict__ pos,
                  float* __restrict__ out) {
    __shared__ TileU L;
    const int t    = threadIdx.x;
    const int wid  = t >> 6;
    const int lane = t & 63;
    const int n_lo = lane & 15;
    const int kg   = lane >> 4;
    const int m0   = blockIdx.x * BM;

    // ---- stage A: 16 rows x 1024 bf16 (32 KB) via global_load_lds.
    // LDS dest is wave-uniform base + lane*16 (linear); the XOR swizzle is
    // applied on the per-lane GLOBAL source address (rule #21 / m173).
#pragma unroll
    for (int c = 0; c < 4; ++c) {
        const int flat = c * 8192 + t * 16;      // dest byte in As
        const int row  = flat >> 11;             // /2048 (row = 2 KB)
        const int colb = flat & 2047;
        const int scolb = colb ^ ((row & 15) << 4);
        const u16* src = Xa + (size_t)(m0 + row) * AI + (scolb >> 1);
        __builtin_amdgcn_global_load_lds(
            (const __attribute__((address_space(1))) void*)src,
            (__attribute__((address_space(3))) void*)(L.bytes + c * 8192 + (wid << 10)),
            16, 0, 0);
    }

    float bv[8];
#pragma unroll
    for (int f = 0; f < 8; ++f) bv[f] = bias[wid * 128 + f * 16 + n_lo];

    f32x4 acc[8];
#pragma unroll
    for (int f = 0; f < 8; ++f) acc[f] = (f32x4)0.0f;

    __syncthreads();   // drains vmcnt: A-tile resident

    // ---- GEMM: K=1024 in 32-elem chunks; 8 n-frags per wave, 1 m-frag.
    const u16* wbase = Wb + (size_t)(wid * 128 + n_lo) * AI + kg * 8;
#pragma unroll 2
    for (int kk = 0; kk < AI; kk += 32) {
        const int cb = kk * 2 + kg * 16;                       // byte col
        bf16x8 a = *reinterpret_cast<const bf16x8*>(
            L.bytes + (n_lo << 11) + (cb ^ (n_lo << 4)));      // swizzled read
        bf16x8 b0, b1, b2, b3;
#pragma unroll
        for (int h = 0; h < 2; ++h) {
            const u16* wp = wbase + (size_t)(h * 4 * 16) * AI + kk;
            b0 = *reinterpret_cast<const bf16x8*>(wp);
            b1 = *reinterpret_cast<const bf16x8*>(wp + (size_t)16 * AI);
            b2 = *reinterpret_cast<const bf16x8*>(wp + (size_t)32 * AI);
            b3 = *reinterpret_cast<const bf16x8*>(wp + (size_t)48 * AI);
            acc[h * 4 + 0] = __builtin_amdgcn_mfma_f32_16x16x32_bf16(a, b0, acc[h * 4 + 0], 0, 0, 0);
            acc[h * 4 + 1] = __builtin_amdgcn_mfma_f32_16x16x32_bf16(a, b1, acc[h * 4 + 1], 0, 0, 0);
            acc[h * 4 + 2] = __builtin_amdgcn_mfma_f32_16x16x32_bf16(a, b2, acc[h * 4 + 2], 0, 0, 0);
            acc[h * 4 + 3] = __builtin_amdgcn_mfma_f32_16x16x32_bf16(a, b3, acc[h * 4 + 3], 0, 0, 0);
        }
    }

    __syncthreads();   // all waves done with As before aliasing it as ys

    // ---- park y (+bias) as bf16 into LDS (aliases As)
#pragma unroll
    for (int f = 0; f < 8; ++f)
#pragma unroll
        for (int r = 0; r < 4; ++r)
            L.ys[kg * 4 + r][wid * 128 + f * 16 + n_lo] = f2bf(acc[f][r] + bv[f]);
    __syncthreads();

    // ---- dense write: 16 rows x 4096 cols, zero-merged via pos[]
    const i32x4* pos4 = reinterpret_cast<const i32x4*>(pos);
#pragma unroll 4
    for (int it = 0; it < 32; ++it) {
        const int idx = it * 512 + t;     // 0..16383
        const int row = idx >> 10;
        const int o4  = idx & 1023;
        i32x4 p = pos4[o4];
        f32x4 v;
        v.x = (p.x >= 0) ? bf2f(L.ys[row][p.x]) : 0.0f;
        v.y = (p.y >= 0) ? bf2f(L.ys[row][p.y]) : 0.0f;
        v.z = (p.z >= 0) ? bf2f(L.ys[row][p.z]) : 0.0f;
        v.w = (p.w >= 0) ? bf2f(L.ys[row][p.w]) : 0.0f;
        reinterpret_cast<f32x4*>(out + (size_t)(m0 + row) * OUT_F)[o4] = v;
    }
}

extern "C" void kernel_launch(void* const* d_in, const int* in_sizes, int n_in,
                              void* d_out, int out_size, void* d_ws, size_t ws_size,
                              hipStream_t stream) {
    const float* x      = (const float*)d_in[0];
    const float* W      = (const float*)d_in[1];
    const float* b      = (const float*)d_in[2];
    const int*   in_idx = (const int*)d_in[3];
    const int*   out_idx= (const int*)d_in[4];
    float* out = (float*)d_out;

    char* ws = (char*)d_ws;
    int* pos = (int*)ws;                                   // 16 KB
    u16* Wb  = (u16*)(ws + 16384);                         // 2 MB
    u16* Xa  = (u16*)(ws + 16384 + 2 * 1024 * 1024);       // 16 MB

    hipMemsetAsync(pos, 0xFF, OUT_F * sizeof(int), stream); // pos = -1
    prep_kernel<<<1024, 256, 0, stream>>>(W, out_idx, Wb, pos);
    gather_kernel<<<M_ROWS, 256, 0, stream>>>(x, in_idx, Xa);
    gemmx_kernel<<<M_ROWS / BM, 512, 0, stream>>>(Xa, Wb, b, pos, out);
}

// Round 4
// 281.943 us; speedup vs baseline: 1.2633x; 1.2633x over previous
//
#include <hip/hip_runtime.h>
#include <hip/hip_bf16.h>

// NeuroselectiveLinear: y = gather(x, in_idx) @ W^T + b scattered into a
// zeroed [B,S,4096] buffer.
// Single fused kernel: each block owns BM=16 full rows -> gathers x directly
// (no Xa staging buffer), runs full-K MFMA GEMM with register-double-buffered
// B stream from a K-chunk-major bf16 W copy (L2-resident), then writes the
// dense 4096-wide rows with zero-merge via inverse pos[] map.

typedef unsigned short u16;
typedef u16   u16x4 __attribute__((ext_vector_type(4)));
typedef int   i32x4 __attribute__((ext_vector_type(4)));
typedef float f32x4 __attribute__((ext_vector_type(4)));
typedef __bf16 bf16x8 __attribute__((ext_vector_type(8)));

constexpr int IN_F  = 4096;
constexpr int OUT_F = 4096;
constexpr int AI    = 1024;      // ACTIVE_IN  (K)
constexpr int AO    = 1024;      // ACTIVE_OUT (N)
constexpr int M_ROWS = 4 * 2048; // 8192
constexpr int BM    = 16;        // rows per block; grid 512 -> 2 blocks/CU

__device__ __forceinline__ u16 f2bf(float f) {
    union { __hip_bfloat16 h; u16 u; } cv;
    cv.h = __float2bfloat16(f);   // RNE
    return cv.u;
}
__device__ __forceinline__ float bf2f(u16 u) {
    union { float f; unsigned int i; } cv;
    cv.i = ((unsigned int)u) << 16;
    return cv.f;
}

// Wb2: K-chunk-major bf16 W. Element (n, k) -> Wb2[(k>>3)*8192 + n*8 + (k&7)].
// A wave's 8 B-fragments (rows wid*128 + f*16 + n_lo, 8 k's) then sit at
// one base + f*256B: immediate-offset folded, coalesced across lanes.
// Also pos[out_idx[j]] = j  (pos pre-memset to -1).
__global__ void prep_kernel(const float* __restrict__ W,
                            const int* __restrict__ out_idx,
                            u16* __restrict__ Wb2, int* __restrict__ pos) {
    int t = blockIdx.x * blockDim.x + threadIdx.x; // 0..262143
    if (t < AO) pos[out_idx[t]] = t;
    const int n  = t >> 8;           // 0..1023
    const int k4 = (t & 255) * 4;    // 0..1020
    f32x4 w = *reinterpret_cast<const f32x4*>(W + (size_t)n * AI + k4);
    u16x4 v;
    v.x = f2bf(w.x); v.y = f2bf(w.y); v.z = f2bf(w.z); v.w = f2bf(w.w);
    *reinterpret_cast<u16x4*>(Wb2 + ((k4 >> 3) << 13) + n * 8 + (k4 & 7)) = v;
}

// Fused gather + GEMM + dense write. 512 thr (8 waves), LDS 33.3 KB,
// VGPR-capped for 4 waves/SIMD -> 2 blocks/CU (phase overlap across blocks).
__global__ __launch_bounds__(512, 4)
void gemmd_kernel(const float* __restrict__ x, const u16* __restrict__ Wb2,
                  const float* __restrict__ bias, const int* __restrict__ in_idx,
                  const int* __restrict__ pos, float* __restrict__ out) {
    // As: [16][1024] bf16, XOR-swizzled (byte col ^= row<<4), 32 KB.
    // ys: [16][1040] bf16 alias after GEMM (As dead), 33.3 KB.
    __shared__ char L[BM * 1040 * 2];

    const int t    = threadIdx.x;
    const int wid  = t >> 6;
    const int lane = t & 63;
    const int n_lo = lane & 15;
    const int kg   = lane >> 4;
    const int m0   = blockIdx.x * BM;

    // ---- gather phase: 16 rows x 1024 active cols, straight from x.
    // 32 threads per row, 32 elements each; swizzled ds_write_b64.
    {
        const int gr = t >> 5;       // row 0..15
        const int gj = t & 31;       // 32 threads per row
        const float* xrow = x + (size_t)(m0 + gr) * IN_F;
        const int kbase = gj * 32;
#pragma unroll
        for (int q = 0; q < 8; ++q) {
            i32x4 idx = *reinterpret_cast<const i32x4*>(in_idx + kbase + q * 4);
            u16x4 v;
            v.x = f2bf(xrow[idx.x]);
            v.y = f2bf(xrow[idx.y]);
            v.z = f2bf(xrow[idx.z]);
            v.w = f2bf(xrow[idx.w]);
            const int cb = (kbase + q * 4) * 2;
            *reinterpret_cast<u16x4*>(L + (gr << 11) + (cb ^ (gr << 4))) = v;
        }
    }

    f32x4 acc[8];
#pragma unroll
    for (int f = 0; f < 8; ++f) acc[f] = (f32x4)0.0f;

    __syncthreads();   // A-tile resident

    // ---- GEMM: K=1024, 32-elem chunks, register-double-buffered B.
    // B-frag base for chunk kk: Wb2 + ((kk + kg*8)>>3)*8192 + (wid*128+n_lo)*8
    const u16* wb0 = Wb2 + (size_t)(kg << 13) + (size_t)(wid * 128 + n_lo) * 8;
    const int abase = n_lo << 11;

    bf16x8 bA[8], bB[8], a0, a1;
#pragma unroll
    for (int f = 0; f < 8; ++f)
        bA[f] = *reinterpret_cast<const bf16x8*>(wb0 + f * 128);
    a0 = *reinterpret_cast<const bf16x8*>(L + abase + ((kg << 4) ^ (n_lo << 4)));

#pragma unroll 1
    for (int kk = 0; kk < AI; kk += 64) {
        {   // prefetch odd half-chunk
            const u16* wb = wb0 + (size_t)((kk + 32) >> 3) * 8192;
#pragma unroll
            for (int f = 0; f < 8; ++f)
                bB[f] = *reinterpret_cast<const bf16x8*>(wb + f * 128);
            const int cb = (kk + 32) * 2 + (kg << 4);
            a1 = *reinterpret_cast<const bf16x8*>(L + abase + (cb ^ (n_lo << 4)));
        }
#pragma unroll
        for (int f = 0; f < 8; ++f)
            acc[f] = __builtin_amdgcn_mfma_f32_16x16x32_bf16(a0, bA[f], acc[f], 0, 0, 0);
        if (kk + 64 < AI) {   // prefetch next even half-chunk
            const u16* wb = wb0 + (size_t)((kk + 64) >> 3) * 8192;
#pragma unroll
            for (int f = 0; f < 8; ++f)
                bA[f] = *reinterpret_cast<const bf16x8*>(wb + f * 128);
            const int cb = (kk + 64) * 2 + (kg << 4);
            a0 = *reinterpret_cast<const bf16x8*>(L + abase + (cb ^ (n_lo << 4)));
        }
#pragma unroll
        for (int f = 0; f < 8; ++f)
            acc[f] = __builtin_amdgcn_mfma_f32_16x16x32_bf16(a1, bB[f], acc[f], 0, 0, 0);
    }

    __syncthreads();   // all waves done reading As before aliasing as ys

    // ---- park y (+bias, loaded only now to keep K-loop VGPRs low) as bf16
    u16* ys = reinterpret_cast<u16*>(L);
#pragma unroll
    for (int f = 0; f < 8; ++f) {
        const float bv = bias[wid * 128 + f * 16 + n_lo];
        const int col = wid * 128 + f * 16 + n_lo;
#pragma unroll
        for (int r = 0; r < 4; ++r)
            ys[(kg * 4 + r) * 1040 + col] = f2bf(acc[f][r] + bv);
    }
    __syncthreads();

    // ---- dense write: 16 rows x 4096 cols, zero-merged via pos[]
    const i32x4* pos4 = reinterpret_cast<const i32x4*>(pos);
#pragma unroll 4
    for (int it = 0; it < 32; ++it) {
        const int idx = it * 512 + t;     // 0..16383
        const int row = idx >> 10;
        const int o4  = idx & 1023;
        i32x4 p = pos4[o4];
        const u16* yr = ys + row * 1040;
        f32x4 v;
        v.x = (p.x >= 0) ? bf2f(yr[p.x]) : 0.0f;
        v.y = (p.y >= 0) ? bf2f(yr[p.y]) : 0.0f;
        v.z = (p.z >= 0) ? bf2f(yr[p.z]) : 0.0f;
        v.w = (p.w >= 0) ? bf2f(yr[p.w]) : 0.0f;
        reinterpret_cast<f32x4*>(out + (size_t)(m0 + row) * OUT_F)[o4] = v;
    }
}

extern "C" void kernel_launch(void* const* d_in, const int* in_sizes, int n_in,
                              void* d_out, int out_size, void* d_ws, size_t ws_size,
                              hipStream_t stream) {
    const float* x      = (const float*)d_in[0];
    const float* W      = (const float*)d_in[1];
    const float* b      = (const float*)d_in[2];
    const int*   in_idx = (const int*)d_in[3];
    const int*   out_idx= (const int*)d_in[4];
    float* out = (float*)d_out;

    char* ws = (char*)d_ws;
    int* pos = (int*)ws;                     // 16 KB
    u16* Wb2 = (u16*)(ws + 16384);           // 2 MB, K-chunk-major

    hipMemsetAsync(pos, 0xFF, OUT_F * sizeof(int), stream); // pos = -1
    prep_kernel<<<1024, 256, 0, stream>>>(W, out_idx, Wb2, pos);
    gemmd_kernel<<<M_ROWS / BM, 512, 0, stream>>>(x, Wb2, b, in_idx, pos, out);
}